// Round 18
// baseline (1345.042 us; speedup 1.0000x reference)
//
#include <hip/hip_runtime.h>
#include <hip/hip_bf16.h>

typedef __hip_bfloat16 bf16;
typedef __attribute__((ext_vector_type(8))) short short8v;
typedef __attribute__((ext_vector_type(4))) float float4v;

#define BB   64
#define CC   3
#define TLEN 256
#define VJ   21
#define DM   128
#define NH   4
#define DH   32
#define KT   9
#define NFR  (BB*TLEN)
#define MTOK (NFR*VJ)          // 344064 tokens
#define NIN  22

// token layout throughout the pipeline: m = ((b*VJ + v)*TLEN + t)  ("[B,V,T,D]")

__device__ __forceinline__ float b2f(bf16 x){ return __bfloat162float(x); }
__device__ __forceinline__ bf16  f2b(float x){ return __float2bfloat16(x); }
__device__ __forceinline__ float hb2f(short s){ return __uint_as_float(((unsigned)(unsigned short)s) << 16); }
__device__ __forceinline__ float lo16(unsigned u){ return __uint_as_float(u << 16); }
__device__ __forceinline__ float hi16(unsigned u){ return __uint_as_float(u & 0xffff0000u); }
__device__ __forceinline__ short bf2s(float x){ bf16 h = f2b(x); return *reinterpret_cast<short*>(&h); }

// ---------------- input dtype detection ----------------
__global__ void detect_dtype(const void* __restrict__ xin, int nus, int* __restrict__ flag){
  const unsigned short* u = (const unsigned short*)xin;
  int lim = nus < 65536 ? nus : 65536;
  int bad = 0;
  for (int k = threadIdx.x; k < lim; k += 256){
    float f = __uint_as_float(((unsigned)u[k]) << 16);
    if (!(fabsf(f) < 1e6f)) bad = 1;
  }
  if (bad) atomicOr(flag, 1);          // flag!=0 => inputs are float32
}

struct ConvArgs { const void* src[NIN]; int off[NIN+1]; };

__global__ void convert_inputs(ConvArgs a, bf16* __restrict__ dst,
                               const int* __restrict__ flag, int total){
  int i = blockIdx.x*256 + threadIdx.x;
  if (i >= total) return;
  bool isf32 = (*flag != 0);
  int k = 0;
  while (i >= a.off[k+1]) ++k;
  int j = i - a.off[k];
  float v;
  if (isf32) v = ((const float*)a.src[k])[j];
  else       v = __uint_as_float(((unsigned)((const unsigned short*)a.src[k])[j]) << 16);
  dst[i] = f2b(v);
}

// ---------------- weight prep ----------------
__global__ void prep_weights(const bf16* __restrict__ wq, const bf16* __restrict__ wk,
                             const bf16* __restrict__ wv, const bf16* __restrict__ wo,
                             const bf16* __restrict__ tw1, const bf16* __restrict__ tw2,
                             bf16* __restrict__ wqT, bf16* __restrict__ wkT,
                             bf16* __restrict__ wvT, bf16* __restrict__ woT,
                             bf16* __restrict__ twT1, bf16* __restrict__ twT2){
  int i = blockIdx.x*256 + threadIdx.x;
  if (i < DM*DM){
    int d = i >> 7, e = i & 127;            // wT[d][e] = w[e][d]
    wqT[i] = wq[e*DM + d];
    wkT[i] = wk[e*DM + d];
    wvT[i] = wv[e*DM + d];
    woT[i] = wo[e*DM + d];
  }
  if (i < KT*DM*DM){
    int c = i & 127; int d = (i >> 7) & 127; int tap = i >> 14;
    twT1[i] = tw1[(d*DM + c)*KT + tap];     // tw [d][c][kt][1]
    twT2[i] = tw2[(d*DM + c)*KT + tap];
  }
}

// ---------------- fused encode + Q/K/V GEMM (b,v uniform per block) ----------------
__global__ __launch_bounds__(512) void qkv_gemm(const bf16* __restrict__ x,
                                                const bf16* __restrict__ cw,
                                                const bf16* __restrict__ cb,
                                                const bf16* __restrict__ je,
                                                const bf16* __restrict__ BtQ,
                                                const bf16* __restrict__ BtK,
                                                const bf16* __restrict__ BtV,
                                                const bf16* __restrict__ bq,
                                                const bf16* __restrict__ bk,
                                                const bf16* __restrict__ bv,
                                                bf16* __restrict__ Oq,
                                                bf16* __restrict__ Ok,
                                                bf16* __restrict__ Ov){
  __shared__ short8v lds[128*16];
  __shared__ float sxf[128][4];              // [t-row][coord]
  const int tid = threadIdx.x;
  const int r0  = blockIdx.x*128;
  const int bvi = r0 >> 8;                   // token block lies inside one (b,v)
  const int t0  = r0 & (TLEN-1);
  const int blk_b = bvi / VJ, blk_v = bvi % VJ;
  {
    int tok = tid >> 2, c = tid & 3;
    if (tok < 128 && c < 3)
      sxf[tok][c] = b2f(x[((size_t)(blk_b*CC + c)*TLEN + t0 + tok)*VJ + blk_v]);
  }
  __syncthreads();
  for (int i = tid; i < 128*16; i += 512){   // compute feat tile (encode fused)
    int row = i >> 4, c0 = i & 15;
    short8v cw0 = *reinterpret_cast<const short8v*>(cw + 0*DM + c0*8);
    short8v cw1 = *reinterpret_cast<const short8v*>(cw + 1*DM + c0*8);
    short8v cw2 = *reinterpret_cast<const short8v*>(cw + 2*DM + c0*8);
    short8v cbv = *reinterpret_cast<const short8v*>(cb + c0*8);
    short8v jev = *reinterpret_cast<const short8v*>(je + blk_v*DM + c0*8);
    float x0 = sxf[row][0], x1 = sxf[row][1], x2 = sxf[row][2];
    short8v out;
    #pragma unroll
    for (int e = 0; e < 8; ++e){
      float f = hb2f(cbv[e]) + hb2f(jev[e]);
      f = fmaf(x0, hb2f(cw0[e]), f);
      f = fmaf(x1, hb2f(cw1[e]), f);
      f = fmaf(x2, hb2f(cw2[e]), f);
      out[e] = bf2s(f);
    }
    lds[row*16 + (c0 ^ (row & 7))] = out;
  }
  __syncthreads();
  const int lane = tid & 63;
  const int wid  = tid >> 6;
  const int rbase = (wid >> 2) * 64;
  const int nt0   = (wid & 3) * 2;
  const int l15 = lane & 15, l4 = lane >> 4;
  #pragma unroll
  for (int w = 0; w < 3; ++w){
    const bf16* Bt  = (w==0) ? BtQ : (w==1) ? BtK : BtV;
    const bf16* bia = (w==0) ? bq  : (w==1) ? bk  : bv;
    bf16*       Out = (w==0) ? Oq  : (w==1) ? Ok  : Ov;
    short8v breg[2][4];
    #pragma unroll
    for (int ntl = 0; ntl < 2; ++ntl)
      #pragma unroll
      for (int ks = 0; ks < 4; ++ks)
        breg[ntl][ks] = *reinterpret_cast<const short8v*>(Bt + ((nt0+ntl)*16 + l15)*DM + ks*32 + l4*8);
    float4v acc[4][2];
    #pragma unroll
    for (int rt = 0; rt < 4; ++rt){ acc[rt][0] = (float4v){0,0,0,0}; acc[rt][1] = (float4v){0,0,0,0}; }
    #pragma unroll
    for (int rt = 0; rt < 4; ++rt){
      const int ldsRow = rbase + rt*16 + l15;
      #pragma unroll
      for (int ks = 0; ks < 4; ++ks){
        short8v a = lds[ldsRow*16 + ((ks*4 + l4) ^ (ldsRow & 7))];
        acc[rt][0] = __builtin_amdgcn_mfma_f32_16x16x32_bf16(a, breg[0][ks], acc[rt][0], 0,0,0);
        acc[rt][1] = __builtin_amdgcn_mfma_f32_16x16x32_bf16(a, breg[1][ks], acc[rt][1], 0,0,0);
      }
    }
    #pragma unroll
    for (int rt = 0; rt < 4; ++rt)
      #pragma unroll
      for (int ntl = 0; ntl < 2; ++ntl){
        int col = (nt0+ntl)*16 + l15;
        float bvv = b2f(bia[col]);
        #pragma unroll
        for (int j = 0; j < 4; ++j)
          Out[(size_t)(r0 + rbase + rt*16 + l4*4 + j)*DM + col] = f2b(acc[rt][ntl][j] + bvv);
      }
  }
}

// ---------------- MFMA conv/GEMM: 256 thr / 4 waves, BM=64 rows ----------------
template<int NTAPS, bool RELU, bool RESID>
__global__ __launch_bounds__(256, 4) void conv_gemm(const bf16* __restrict__ A,
                                                    const bf16* __restrict__ Bt,   // [NTAPS][128][128]
                                                    const bf16* __restrict__ bias,
                                                    const bf16* resid,             // may alias Cout
                                                    bf16* Cout){
  constexpr int HT   = NTAPS/2;               // 4 for 9-tap, 0 for 1x1
  constexpr int ROWS = 64 + 2*HT;             // 72 or 64
  __shared__ short8v lds[ROWS*16];            // [row][chunk ^ (row&7)]
  const int tid = threadIdx.x;
  const int r0  = blockIdx.x*64;
  const int t0  = r0 & (TLEN-1);              // block lies inside one (b,v)
  const long mb = r0 - t0;                    // first token of this (b,v)
  for (int i = tid; i < ROWS*16; i += 256){
    int row = i >> 4, c0 = i & 15;
    int t = t0 + row - HT;
    if (t < 0) t = 0;
    if (t > TLEN-1) t = TLEN-1;               // clamped rows only feed invalid taps
    lds[row*16 + (c0 ^ (row & 7))] = *reinterpret_cast<const short8v*>(A + (mb + t)*DM + c0*8);
  }
  __syncthreads();
  const int lane = tid & 63;
  const int wid  = tid >> 6;
  const int nt0  = wid * 2;                   // col-tile pair
  const int l15 = lane & 15, l4 = lane >> 4;
  float4v acc[4][2];
  #pragma unroll
  for (int rt = 0; rt < 4; ++rt){ acc[rt][0] = (float4v){0,0,0,0}; acc[rt][1] = (float4v){0,0,0,0}; }

  #pragma unroll
  for (int tap = 0; tap < NTAPS; ++tap){
    const bf16* Btap = Bt + (size_t)tap*DM*DM;
    short8v breg[2][4];
    #pragma unroll
    for (int ntl = 0; ntl < 2; ++ntl)
      #pragma unroll
      for (int ks = 0; ks < 4; ++ks)
        breg[ntl][ks] = *reinterpret_cast<const short8v*>(Btap + ((nt0+ntl)*16 + l15)*DM + ks*32 + l4*8);
    const int dt = tap - HT;
    #pragma unroll
    for (int rt = 0; rt < 4; ++rt){
      const int tl = rt*16 + l15;             // local output t-offset (0..63)
      bool valid = true;
      if (NTAPS > 1){
        int ts = t0 + tl + dt;
        valid = (ts >= 0) && (ts < TLEN);
      }
      const int ldsRow = tl + HT + dt;        // 0..ROWS-1
      #pragma unroll
      for (int ks = 0; ks < 4; ++ks){
        short8v a = lds[ldsRow*16 + ((ks*4 + l4) ^ (ldsRow & 7))];
        if (NTAPS > 1 && !valid) a = (short8v){0,0,0,0,0,0,0,0};
        acc[rt][0] = __builtin_amdgcn_mfma_f32_16x16x32_bf16(a, breg[0][ks], acc[rt][0], 0,0,0);
        acc[rt][1] = __builtin_amdgcn_mfma_f32_16x16x32_bf16(a, breg[1][ks], acc[rt][1], 0,0,0);
      }
    }
  }
  #pragma unroll
  for (int rt = 0; rt < 4; ++rt){
    #pragma unroll
    for (int ntl = 0; ntl < 2; ++ntl){
      int col = (nt0+ntl)*16 + l15;
      float bv = b2f(bias[col]);
      #pragma unroll
      for (int j = 0; j < 4; ++j){
        size_t idx = (size_t)(r0 + rt*16 + l4*4 + j)*DM + col;
        float val = acc[rt][ntl][j] + bv;
        if (RESID) val += b2f(resid[idx]);     // read-before-write, same thread
        if (RELU) val = fmaxf(val, 0.f);
        Cout[idx] = f2b(val);
      }
    }
  }
}

// ---------------- attention core v5: MFMA QK^T/PV + fused wo + fused agg + fused gcn1 ----------------
// LDS pool (aliased):
//   [0      .. 5712 )  sQ  -> sao  [32][136] @0
//   [5712   .. 11424)  sK  -> (sfeat tail)
//   [11424  .. 20128)  sV  -> sfeat[32][136] @8704
//   [20128  .. 27184)  sc f32[1764]
//   [27184  .. 37424)  sP bf16[4][32][40]  -> sagg[32][136] @27184
//   [37424  .. 38320)  sgb | [38320..39216) sAn | [39216..39552) rmax | [39552..39888) rinv
#define POOLSZ 39936
__global__ __launch_bounds__(256) void attn_core(const bf16* __restrict__ Q,
                                                 const bf16* __restrict__ K,
                                                 const bf16* __restrict__ V,
                                                 const bf16* __restrict__ gbias,
                                                 const bf16* __restrict__ An,
                                                 const bf16* __restrict__ woT,   // [n][k]
                                                 const bf16* __restrict__ bo,
                                                 const bf16* __restrict__ gw1,   // [n][k]
                                                 const bf16* __restrict__ gb1,
                                                 float* __restrict__ attn_out,
                                                 bf16* __restrict__ feat_out,
                                                 bf16* __restrict__ y_out){
  __shared__ __align__(16) char pool[POOLSZ];
  bf16*  sQ   = (bf16*) (pool + 0);
  bf16*  sK   = (bf16*) (pool + 5712);
  bf16*  sV   = (bf16*) (pool + 11424);
  float* sc   = (float*)(pool + 20128);
  bf16*  sP   = (bf16*) (pool + 27184);
  bf16*  sgb  = (bf16*) (pool + 37424);
  bf16*  sAn  = (bf16*) (pool + 38320);
  float* rmax = (float*)(pool + 39216);
  float* rinv = (float*)(pool + 39552);
  bf16*  sao  = (bf16*) (pool + 0);       // alias over sQ/sK (dead after scores)
  bf16*  sfeat= (bf16*) (pool + 8704);    // alias over sK-end/sV (sV dead after PV)
  bf16*  sagg = (bf16*) (pool + 27184);   // alias over sP (dead after PV)

  const int n = blockIdx.x;
  const int bb = n / TLEN, t = n % TLEN;
  const int tid = threadIdx.x;
  const int lane = tid & 63;
  const int wid  = tid >> 6;              // wave = head
  const int l15 = lane & 15, l4 = lane >> 4;

  for (int i = tid; i < VJ*VJ; i += 256){ sgb[i] = gbias[i]; sAn[i] = An[i]; }
  for (int i = tid; i < 2*VJ*16; i += 256){
    int c0 = i & 15; int v = (i >> 4) % VJ; int w = i / (16*VJ);
    size_t m = ((size_t)bb*VJ + v)*TLEN + t;
    const bf16* src = (w==0 ? Q : K) + m*DM + c0*8;
    bf16* dst = (w==0 ? sQ : sK) + v*136 + c0*8;
    *reinterpret_cast<short8v*>(dst) = *reinterpret_cast<const short8v*>(src);
  }
  for (int i = tid; i < 32*16; i += 256){
    int c0 = i & 15; int v = i >> 4;
    short8v val = (short8v){0,0,0,0,0,0,0,0};
    if (v < VJ){
      size_t m = ((size_t)bb*VJ + v)*TLEN + t;
      val = *reinterpret_cast<const short8v*>(V + m*DM + c0*8);
    }
    *reinterpret_cast<short8v*>(sV + v*136 + c0*8) = val;   // rows >=21 true zeros
  }
  for (int i = tid; i < 4*32*40/8; i += 256)
    reinterpret_cast<short8v*>(sP)[i] = (short8v){0,0,0,0,0,0,0,0};
  __syncthreads();

  // ---- scores via MFMA: wave h (M=21,N=21,K=32 -> 2x2 tiles) ----
  const float scale = 0.17677669529663687f;   // 1/sqrt(32)
  {
    const int h = wid;
    short8v aq[2], bk2[2];
    #pragma unroll
    for (int mt = 0; mt < 2; ++mt){
      int i = mt*16 + l15; if (i > VJ-1) i = VJ-1;
      aq[mt] = *reinterpret_cast<const short8v*>(sQ + i*136 + h*DH + l4*8);
    }
    #pragma unroll
    for (int nt = 0; nt < 2; ++nt){
      int j = nt*16 + l15; if (j > VJ-1) j = VJ-1;
      bk2[nt] = *reinterpret_cast<const short8v*>(sK + j*136 + h*DH + l4*8);
    }
    float4v cs[2][2];
    #pragma unroll
    for (int mt = 0; mt < 2; ++mt)
      #pragma unroll
      for (int nt = 0; nt < 2; ++nt){
        cs[mt][nt] = (float4v){0,0,0,0};
        cs[mt][nt] = __builtin_amdgcn_mfma_f32_16x16x32_bf16(aq[mt], bk2[nt], cs[mt][nt], 0,0,0);
      }
    #pragma unroll
    for (int mt = 0; mt < 2; ++mt)
      #pragma unroll
      for (int nt = 0; nt < 2; ++nt){
        int j = nt*16 + l15;
        #pragma unroll
        for (int jj = 0; jj < 4; ++jj){
          int i = mt*16 + l4*4 + jj;
          if (i < VJ && j < VJ)
            sc[(h*VJ + i)*VJ + j] = cs[mt][nt][jj]*scale + b2f(sgb[i*VJ + j]);
        }
      }
  }
  __syncthreads();
  // ---- softmax stats ----
  for (int r = tid; r < NH*VJ; r += 256){
    float m = -1e30f;
    for (int j = 0; j < VJ; ++j) m = fmaxf(m, sc[r*VJ + j]);
    float s = 0.f;
    for (int j = 0; j < VJ; ++j) s += __expf(sc[r*VJ + j] - m);
    rmax[r] = m; rinv[r] = 1.0f/s;
  }
  __syncthreads();
  // ---- normalize: write attn_out (f32) + sP (bf16, padded) ----
  for (int idx = tid; idx < NH*VJ*VJ; idx += 256){
    int r = idx / VJ;
    int j = idx % VJ, i2 = r % VJ, h = idx/(VJ*VJ);
    float e = __expf(sc[idx] - rmax[r]) * rinv[r];
    attn_out[(size_t)n*(NH*VJ*VJ) + idx] = e;
    sP[(h*32 + i2)*40 + j] = f2b(e);
  }
  __syncthreads();
  // ---- PV via MFMA: wave h: ao[:, h*32..h*32+31] ----
  float4v cp[2][2];
  {
    const int h = wid;
    short8v pa[2];
    #pragma unroll
    for (int mt = 0; mt < 2; ++mt){
      int i = mt*16 + l15;                      // rows >=21 are zeros
      pa[mt] = *reinterpret_cast<const short8v*>(sP + (h*32 + i)*40 + l4*8);
    }
    short8v bv2[2];
    #pragma unroll
    for (int nt = 0; nt < 2; ++nt){
      #pragma unroll
      for (int e = 0; e < 8; ++e)
        bv2[nt][e] = *reinterpret_cast<const short*>(sV + (l4*8 + e)*136 + h*DH + nt*16 + l15);
    }
    #pragma unroll
    for (int mt = 0; mt < 2; ++mt)
      #pragma unroll
      for (int nt = 0; nt < 2; ++nt){
        cp[mt][nt] = (float4v){0,0,0,0};
        cp[mt][nt] = __builtin_amdgcn_mfma_f32_16x16x32_bf16(pa[mt], bv2[nt], cp[mt][nt], 0,0,0);
      }
  }
  __syncthreads();                              // all PV reads of sV/sP done
  // ---- write ao -> sao; zero rows >= VJ ----
  for (int i = tid; i < (32-VJ)*16; i += 256){
    int row = VJ + i/16, c0 = i & 15;
    *reinterpret_cast<short8v*>(sao + row*136 + c0*8) = (short8v){0,0,0,0,0,0,0,0};
  }
  {
    const int h = wid;
    #pragma unroll
    for (int mt = 0; mt < 2; ++mt)
      #pragma unroll
      for (int nt = 0; nt < 2; ++nt){
        int d = h*DH + nt*16 + l15;
        #pragma unroll
        for (int jj = 0; jj < 4; ++jj){
          int i = mt*16 + l4*4 + jj;
          if (i < VJ) sao[i*136 + d] = f2b(cp[mt][nt][jj]);
        }
      }
  }
  __syncthreads();
  // ---- wo GEMM: M=32, N=128, K=128 ----
  float4v acc[2][2];
  #pragma unroll
  for (int mt = 0; mt < 2; ++mt){ acc[mt][0] = (float4v){0,0,0,0}; acc[mt][1] = (float4v){0,0,0,0}; }
  #pragma unroll
  for (int ks = 0; ks < 4; ++ks){
    short8v bfr[2];
    #pragma unroll
    for (int ct = 0; ct < 2; ++ct)
      bfr[ct] = *reinterpret_cast<const short8v*>(woT + (wid*32 + ct*16 + l15)*DM + ks*32 + l4*8);
    #pragma unroll
    for (int mt = 0; mt < 2; ++mt){
      int row = mt*16 + l15;
      short8v a = *reinterpret_cast<const short8v*>(sao + row*136 + ks*32 + l4*8);
      acc[mt][0] = __builtin_amdgcn_mfma_f32_16x16x32_bf16(a, bfr[0], acc[mt][0], 0,0,0);
      acc[mt][1] = __builtin_amdgcn_mfma_f32_16x16x32_bf16(a, bfr[1], acc[mt][1], 0,0,0);
    }
  }
  #pragma unroll
  for (int mt = 0; mt < 2; ++mt){
    #pragma unroll
    for (int ct = 0; ct < 2; ++ct){
      int col = wid*32 + ct*16 + l15;
      float bov = b2f(bo[col]);
      #pragma unroll
      for (int j = 0; j < 4; ++j){
        int row = mt*16 + l4*4 + j;
        float fv = acc[mt][ct][j] + bov;
        sfeat[row*136 + col] = f2b(fv);
        if (row < VJ)
          feat_out[(((size_t)bb*VJ + row)*TLEN + t)*DM + col] = f2b(fv);
      }
    }
  }
  __syncthreads();
  // ---- agg GEMM: agg[w][d] = sum_u An[u][w]*feat[u][d]; K=32 ----
  float4v acg[2][2];
  #pragma unroll
  for (int mt = 0; mt < 2; ++mt){ acg[mt][0] = (float4v){0,0,0,0}; acg[mt][1] = (float4v){0,0,0,0}; }
  short8v afr[2];
  #pragma unroll
  for (int mt = 0; mt < 2; ++mt){
    int w = mt*16 + l15;
    #pragma unroll
    for (int e = 0; e < 8; ++e){
      int k = l4*8 + e;
      short vsv = 0;
      if (k < VJ && w < VJ) vsv = *reinterpret_cast<const short*>(&sAn[k*VJ + w]);
      afr[mt][e] = vsv;
    }
  }
  #pragma unroll
  for (int ct = 0; ct < 2; ++ct){
    int d = wid*32 + ct*16 + l15;
    short8v bfr;
    #pragma unroll
    for (int e = 0; e < 8; ++e){
      int k = l4*8 + e;
      bfr[e] = *reinterpret_cast<const short*>(sfeat + k*136 + d);
    }
    #pragma unroll
    for (int mt = 0; mt < 2; ++mt)
      acg[mt][ct] = __builtin_amdgcn_mfma_f32_16x16x32_bf16(afr[mt], bfr, acg[mt][ct], 0,0,0);
  }
  // stash agg (all 32 rows, finite) -> sagg for the gcn GEMM
  #pragma unroll
  for (int mt = 0; mt < 2; ++mt)
    #pragma unroll
    for (int ct = 0; ct < 2; ++ct){
      int col = wid*32 + ct*16 + l15;
      #pragma unroll
      for (int j = 0; j < 4; ++j)
        sagg[(mt*16 + l4*4 + j)*136 + col] = f2b(acg[mt][ct][j]);
    }
  __syncthreads();
  // ---- gcn1 GEMM: y1 = relu(agg @ gw1 + gb1); M=32, N=128, K=128 ----
  float4v acy[2][2];
  #pragma unroll
  for (int mt = 0; mt < 2; ++mt){ acy[mt][0] = (float4v){0,0,0,0}; acy[mt][1] = (float4v){0,0,0,0}; }
  #pragma unroll
  for (int ks = 0; ks < 4; ++ks){
    short8v bfr[2];
    #pragma unroll
    for (int ct = 0; ct < 2; ++ct)
      bfr[ct] = *reinterpret_cast<const short8v*>(gw1 + (wid*32 + ct*16 + l15)*DM + ks*32 + l4*8);
    #pragma unroll
    for (int mt = 0; mt < 2; ++mt){
      int row = mt*16 + l15;
      short8v a = *reinterpret_cast<const short8v*>(sagg + row*136 + ks*32 + l4*8);
      acy[mt][0] = __builtin_amdgcn_mfma_f32_16x16x32_bf16(a, bfr[0], acy[mt][0], 0,0,0);
      acy[mt][1] = __builtin_amdgcn_mfma_f32_16x16x32_bf16(a, bfr[1], acy[mt][1], 0,0,0);
    }
  }
  #pragma unroll
  for (int mt = 0; mt < 2; ++mt){
    #pragma unroll
    for (int ct = 0; ct < 2; ++ct){
      int col = wid*32 + ct*16 + l15;
      float gbv = b2f(gb1[col]);
      #pragma unroll
      for (int j = 0; j < 4; ++j){
        int w = mt*16 + l4*4 + j;
        if (w < VJ)
          y_out[(((size_t)bb*VJ + w)*TLEN + t)*DM + col] = f2b(fmaxf(acy[mt][ct][j] + gbv, 0.f));
      }
    }
  }
}

// ---------------- fused agg + gcn 1x1 (ST-GCN block 2 front half) ----------------
__global__ __launch_bounds__(256) void agg_gcn(const bf16* __restrict__ fin,
                                               const bf16* __restrict__ An,
                                               const bf16* __restrict__ gw,   // [n][k]
                                               const bf16* __restrict__ gb,
                                               bf16* __restrict__ yout){
  __shared__ __align__(16) bf16 sfeat[32*136];
  __shared__ __align__(16) bf16 sagg[32*136];
  __shared__ bf16 sAn[VJ*VJ];
  const int n = blockIdx.x;
  const int bb = n / TLEN, t = n % TLEN;
  const int tid = threadIdx.x;
  const int lane = tid & 63;
  const int wid  = tid >> 6;
  const int l15 = lane & 15, l4 = lane >> 4;
  for (int i = tid; i < VJ*VJ; i += 256) sAn[i] = An[i];
  for (int i = tid; i < 32*16; i += 256){
    int c0 = i & 15; int v = i >> 4;
    short8v val = (short8v){0,0,0,0,0,0,0,0};
    if (v < VJ){
      size_t m = ((size_t)bb*VJ + v)*TLEN + t;
      val = *reinterpret_cast<const short8v*>(fin + m*DM + c0*8);
    }
    *reinterpret_cast<short8v*>(sfeat + v*136 + c0*8) = val;   // rows >=21 zeros
  }
  __syncthreads();
  // agg GEMM (K=32)
  float4v acg[2][2];
  #pragma unroll
  for (int mt = 0; mt < 2; ++mt){ acg[mt][0] = (float4v){0,0,0,0}; acg[mt][1] = (float4v){0,0,0,0}; }
  short8v afr[2];
  #pragma unroll
  for (int mt = 0; mt < 2; ++mt){
    int w = mt*16 + l15;
    #pragma unroll
    for (int e = 0; e < 8; ++e){
      int k = l4*8 + e;
      short vsv = 0;
      if (k < VJ && w < VJ) vsv = *reinterpret_cast<const short*>(&sAn[k*VJ + w]);
      afr[mt][e] = vsv;
    }
  }
  #pragma unroll
  for (int ct = 0; ct < 2; ++ct){
    int d = wid*32 + ct*16 + l15;
    short8v bfr;
    #pragma unroll
    for (int e = 0; e < 8; ++e){
      int k = l4*8 + e;
      bfr[e] = *reinterpret_cast<const short*>(sfeat + k*136 + d);
    }
    #pragma unroll
    for (int mt = 0; mt < 2; ++mt)
      acg[mt][ct] = __builtin_amdgcn_mfma_f32_16x16x32_bf16(afr[mt], bfr, acg[mt][ct], 0,0,0);
  }
  #pragma unroll
  for (int mt = 0; mt < 2; ++mt)
    #pragma unroll
    for (int ct = 0; ct < 2; ++ct){
      int col = wid*32 + ct*16 + l15;
      #pragma unroll
      for (int j = 0; j < 4; ++j)
        sagg[(mt*16 + l4*4 + j)*136 + col] = f2b(acg[mt][ct][j]);
    }
  __syncthreads();
  // gcn GEMM (K=128) + relu
  float4v acy[2][2];
  #pragma unroll
  for (int mt = 0; mt < 2; ++mt){ acy[mt][0] = (float4v){0,0,0,0}; acy[mt][1] = (float4v){0,0,0,0}; }
  #pragma unroll
  for (int ks = 0; ks < 4; ++ks){
    short8v bfr[2];
    #pragma unroll
    for (int ct = 0; ct < 2; ++ct)
      bfr[ct] = *reinterpret_cast<const short8v*>(gw + (wid*32 + ct*16 + l15)*DM + ks*32 + l4*8);
    #pragma unroll
    for (int mt = 0; mt < 2; ++mt){
      int row = mt*16 + l15;
      short8v a = *reinterpret_cast<const short8v*>(sagg + row*136 + ks*32 + l4*8);
      acy[mt][0] = __builtin_amdgcn_mfma_f32_16x16x32_bf16(a, bfr[0], acy[mt][0], 0,0,0);
      acy[mt][1] = __builtin_amdgcn_mfma_f32_16x16x32_bf16(a, bfr[1], acy[mt][1], 0,0,0);
    }
  }
  #pragma unroll
  for (int mt = 0; mt < 2; ++mt){
    #pragma unroll
    for (int ct = 0; ct < 2; ++ct){
      int col = wid*32 + ct*16 + l15;
      float gbv = b2f(gb[col]);
      #pragma unroll
      for (int j = 0; j < 4; ++j){
        int w = mt*16 + l4*4 + j;
        if (w < VJ)
          yout[(((size_t)bb*VJ + w)*TLEN + t)*DM + col] = f2b(fmaxf(acy[mt][ct][j] + gbv, 0.f));
      }
    }
  }
}

// ---------------- [B,V,T,D] bf16 -> [B,D,T,V] f32 transpose into d_out ----------------
__global__ __launch_bounds__(256) void transpose_out(const bf16* __restrict__ fin,
                                                     float* __restrict__ fout){
  const int bid = blockIdx.x;
  const int b   = bid >> 5;
  const int rem = bid & 31;
  const int t0  = (rem >> 2) * 32;
  const int d0  = (rem & 3) * 32;
  __shared__ bf16 tile[32][VJ][33];
  const int tid = threadIdx.x;
  for (int idx = tid; idx < 32*VJ*32; idx += 256){
    int dl = idx & 31;
    int v  = (idx >> 5) % VJ;
    int tl = idx / (32*VJ);
    tile[tl][v][dl] = fin[(((size_t)b*VJ + v)*TLEN + t0 + tl)*DM + d0 + dl];
  }
  __syncthreads();
  for (int idx = tid; idx < 32*VJ*32; idx += 256){
    int j  = idx % (32*VJ);
    int dl = idx / (32*VJ);
    int tl = j / VJ, v = j % VJ;
    fout[((size_t)(b*DM + d0 + dl)*TLEN + t0 + tl)*VJ + v] = b2f(tile[tl][v][dl]);
  }
}

extern "C" void kernel_launch(void* const* d_in, const int* in_sizes, int n_in,
                              void* d_out, int out_size, void* d_ws, size_t ws_size,
                              hipStream_t stream){
  const size_t featElems = (size_t)MTOK*DM;        // 44,040,192
  float* outf    = (float*)d_out;                  // [B,D,T,V] f32 (final)
  float* attnOut = outf + featElems;               // [N,H,V,V] f32 (final)
  bf16* qbuf = (bf16*)d_out;                       // scratch until transpose_out
  bf16* kbuf = qbuf + featElems;

  char* wp = (char*)d_ws;
  auto alloc = [&](size_t bytes)->char*{ char* p = wp; wp += (bytes + 15) & ~(size_t)15; return p; };
  int*  flag = (int*)alloc(16);
  ConvArgs ca; int total = 0;
  for (int i = 0; i < NIN; ++i){ ca.src[i] = d_in[i]; ca.off[i] = total; total += in_sizes[i]; }
  ca.off[NIN] = total;
  bf16* cin   = (bf16*)alloc((size_t)total*2);
  bf16* wqT   = (bf16*)alloc(DM*DM*2);
  bf16* wkT   = (bf16*)alloc(DM*DM*2);
  bf16* wvT   = (bf16*)alloc(DM*DM*2);
  bf16* woT   = (bf16*)alloc(DM*DM*2);
  bf16* twT1  = (bf16*)alloc(KT*DM*DM*2);
  bf16* twT2  = (bf16*)alloc(KT*DM*DM*2);
  bf16* featA = (bf16*)alloc(featElems*2);         // feat0 / running feature map
  bf16* bufV  = (bf16*)alloc(featElems*2);         // V
  if ((size_t)(wp - (char*)d_ws) > ws_size) return;

  const bf16* x    = cin + ca.off[0];
  const bf16* cw   = cin + ca.off[1];
  const bf16* cb   = cin + ca.off[2];
  const bf16* je   = cin + ca.off[3];
  const bf16* gbias= cin + ca.off[4];
  const bf16* wq   = cin + ca.off[5];
  const bf16* bq   = cin + ca.off[6];
  const bf16* wk   = cin + ca.off[7];
  const bf16* bk   = cin + ca.off[8];
  const bf16* wv   = cin + ca.off[9];
  const bf16* bv   = cin + ca.off[10];
  const bf16* wo   = cin + ca.off[11];
  const bf16* bo   = cin + ca.off[12];
  const bf16* gw1  = cin + ca.off[13];
  const bf16* gb1  = cin + ca.off[14];
  const bf16* tw1  = cin + ca.off[15];
  const bf16* tb1  = cin + ca.off[16];
  const bf16* gw2  = cin + ca.off[17];
  const bf16* gb2  = cin + ca.off[18];
  const bf16* tw2  = cin + ca.off[19];
  const bf16* tb2  = cin + ca.off[20];
  const bf16* An   = cin + ca.off[21];

  const int GB  = MTOK/128;                        // 2688 blocks (qkv)
  const int GB2 = MTOK/64;                         // 5376 blocks (conv)
  hipMemsetAsync(flag, 0, sizeof(int), stream);
  detect_dtype<<<1, 256, 0, stream>>>(d_in[0], in_sizes[0], flag);
  convert_inputs<<<(total + 255)/256, 256, 0, stream>>>(ca, cin, flag, total);
  prep_weights<<<(KT*DM*DM + 255)/256, 256, 0, stream>>>(wq, wk, wv, wo, tw1, tw2,
                                                         wqT, wkT, wvT, woT, twT1, twT2);
  qkv_gemm<<<GB, 512, 0, stream>>>(x, cw, cb, je, wqT, wkT, wvT, bq, bk, bv,
                                   qbuf, kbuf, bufV);
  attn_core<<<NFR, 256, 0, stream>>>(qbuf, kbuf, bufV, gbias, An, woT, bo, gw1, gb1,
                                     attnOut, featA, qbuf);   // y1 -> qbuf
  // ST-GCN block 1: temporal conv
  conv_gemm<9,true,true><<<GB2, 256, 0, stream>>>(qbuf, twT1, tb1, featA, featA);
  // ST-GCN block 2
  agg_gcn<<<NFR, 256, 0, stream>>>(featA, An, gw2, gb2, qbuf);
  conv_gemm<9,true,true><<<GB2, 256, 0, stream>>>(qbuf, twT2, tb2, featA, featA);
  transpose_out<<<BB*(TLEN/32)*(DM/32), 256, 0, stream>>>(featA, outf);
}

// Round 19
// 1254.576 us; speedup vs baseline: 1.0721x; 1.0721x over previous
//
#include <hip/hip_runtime.h>
#include <hip/hip_bf16.h>

typedef __hip_bfloat16 bf16;
typedef __attribute__((ext_vector_type(8))) short short8v;
typedef __attribute__((ext_vector_type(4))) float float4v;

#define BB   64
#define CC   3
#define TLEN 256
#define VJ   21
#define DM   128
#define NH   4
#define DH   32
#define KT   9
#define NFR  (BB*TLEN)
#define MTOK (NFR*VJ)          // 344064 tokens
#define NIN  22

// token layout throughout the pipeline: m = ((b*VJ + v)*TLEN + t)  ("[B,V,T,D]")

__device__ __forceinline__ float b2f(bf16 x){ return __bfloat162float(x); }
__device__ __forceinline__ bf16  f2b(float x){ return __float2bfloat16(x); }
__device__ __forceinline__ float hb2f(short s){ return __uint_as_float(((unsigned)(unsigned short)s) << 16); }
__device__ __forceinline__ float lo16(unsigned u){ return __uint_as_float(u << 16); }
__device__ __forceinline__ float hi16(unsigned u){ return __uint_as_float(u & 0xffff0000u); }
__device__ __forceinline__ short bf2s(float x){ bf16 h = f2b(x); return *reinterpret_cast<short*>(&h); }

// ---------------- input dtype detection ----------------
__global__ void detect_dtype(const void* __restrict__ xin, int nus, int* __restrict__ flag){
  const unsigned short* u = (const unsigned short*)xin;
  int lim = nus < 65536 ? nus : 65536;
  int bad = 0;
  for (int k = threadIdx.x; k < lim; k += 256){
    float f = __uint_as_float(((unsigned)u[k]) << 16);
    if (!(fabsf(f) < 1e6f)) bad = 1;
  }
  if (bad) atomicOr(flag, 1);          // flag!=0 => inputs are float32
}

struct ConvArgs { const void* src[NIN]; int off[NIN+1]; };

__global__ void convert_inputs(ConvArgs a, bf16* __restrict__ dst,
                               const int* __restrict__ flag, int total){
  int i = blockIdx.x*256 + threadIdx.x;
  if (i >= total) return;
  bool isf32 = (*flag != 0);
  int k = 0;
  while (i >= a.off[k+1]) ++k;
  int j = i - a.off[k];
  float v;
  if (isf32) v = ((const float*)a.src[k])[j];
  else       v = __uint_as_float(((unsigned)((const unsigned short*)a.src[k])[j]) << 16);
  dst[i] = f2b(v);
}

// ---------------- weight prep ----------------
__global__ void prep_weights(const bf16* __restrict__ wq, const bf16* __restrict__ wk,
                             const bf16* __restrict__ wv, const bf16* __restrict__ wo,
                             const bf16* __restrict__ tw1, const bf16* __restrict__ tw2,
                             bf16* __restrict__ wqT, bf16* __restrict__ wkT,
                             bf16* __restrict__ wvT, bf16* __restrict__ woT,
                             bf16* __restrict__ twT1, bf16* __restrict__ twT2){
  int i = blockIdx.x*256 + threadIdx.x;
  if (i < DM*DM){
    int d = i >> 7, e = i & 127;            // wT[d][e] = w[e][d]
    wqT[i] = wq[e*DM + d];
    wkT[i] = wk[e*DM + d];
    wvT[i] = wv[e*DM + d];
    woT[i] = wo[e*DM + d];
  }
  if (i < KT*DM*DM){
    int c = i & 127; int d = (i >> 7) & 127; int tap = i >> 14;
    twT1[i] = tw1[(d*DM + c)*KT + tap];     // tw [d][c][kt][1]
    twT2[i] = tw2[(d*DM + c)*KT + tap];
  }
}

// ---------------- fused encode + Q/K/V GEMM (b,v uniform per block) ----------------
__global__ __launch_bounds__(512) void qkv_gemm(const bf16* __restrict__ x,
                                                const bf16* __restrict__ cw,
                                                const bf16* __restrict__ cb,
                                                const bf16* __restrict__ je,
                                                const bf16* __restrict__ BtQ,
                                                const bf16* __restrict__ BtK,
                                                const bf16* __restrict__ BtV,
                                                const bf16* __restrict__ bq,
                                                const bf16* __restrict__ bk,
                                                const bf16* __restrict__ bv,
                                                bf16* __restrict__ Oq,
                                                bf16* __restrict__ Ok,
                                                bf16* __restrict__ Ov){
  __shared__ short8v lds[128*16];
  __shared__ float sxf[128][4];              // [t-row][coord]
  const int tid = threadIdx.x;
  const int r0  = blockIdx.x*128;
  const int bvi = r0 >> 8;                   // token block lies inside one (b,v)
  const int t0  = r0 & (TLEN-1);
  const int blk_b = bvi / VJ, blk_v = bvi % VJ;
  {
    int tok = tid >> 2, c = tid & 3;
    if (tok < 128 && c < 3)
      sxf[tok][c] = b2f(x[((size_t)(blk_b*CC + c)*TLEN + t0 + tok)*VJ + blk_v]);
  }
  __syncthreads();
  for (int i = tid; i < 128*16; i += 512){   // compute feat tile (encode fused)
    int row = i >> 4, c0 = i & 15;
    short8v cw0 = *reinterpret_cast<const short8v*>(cw + 0*DM + c0*8);
    short8v cw1 = *reinterpret_cast<const short8v*>(cw + 1*DM + c0*8);
    short8v cw2 = *reinterpret_cast<const short8v*>(cw + 2*DM + c0*8);
    short8v cbv = *reinterpret_cast<const short8v*>(cb + c0*8);
    short8v jev = *reinterpret_cast<const short8v*>(je + blk_v*DM + c0*8);
    float x0 = sxf[row][0], x1 = sxf[row][1], x2 = sxf[row][2];
    short8v out;
    #pragma unroll
    for (int e = 0; e < 8; ++e){
      float f = hb2f(cbv[e]) + hb2f(jev[e]);
      f = fmaf(x0, hb2f(cw0[e]), f);
      f = fmaf(x1, hb2f(cw1[e]), f);
      f = fmaf(x2, hb2f(cw2[e]), f);
      out[e] = bf2s(f);
    }
    lds[row*16 + (c0 ^ (row & 7))] = out;
  }
  __syncthreads();
  const int lane = tid & 63;
  const int wid  = tid >> 6;
  const int rbase = (wid >> 2) * 64;
  const int nt0   = (wid & 3) * 2;
  const int l15 = lane & 15, l4 = lane >> 4;
  #pragma unroll
  for (int w = 0; w < 3; ++w){
    const bf16* Bt  = (w==0) ? BtQ : (w==1) ? BtK : BtV;
    const bf16* bia = (w==0) ? bq  : (w==1) ? bk  : bv;
    bf16*       Out = (w==0) ? Oq  : (w==1) ? Ok  : Ov;
    short8v breg[2][4];
    #pragma unroll
    for (int ntl = 0; ntl < 2; ++ntl)
      #pragma unroll
      for (int ks = 0; ks < 4; ++ks)
        breg[ntl][ks] = *reinterpret_cast<const short8v*>(Bt + ((nt0+ntl)*16 + l15)*DM + ks*32 + l4*8);
    float4v acc[4][2];
    #pragma unroll
    for (int rt = 0; rt < 4; ++rt){ acc[rt][0] = (float4v){0,0,0,0}; acc[rt][1] = (float4v){0,0,0,0}; }
    #pragma unroll
    for (int rt = 0; rt < 4; ++rt){
      const int ldsRow = rbase + rt*16 + l15;
      #pragma unroll
      for (int ks = 0; ks < 4; ++ks){
        short8v a = lds[ldsRow*16 + ((ks*4 + l4) ^ (ldsRow & 7))];
        acc[rt][0] = __builtin_amdgcn_mfma_f32_16x16x32_bf16(a, breg[0][ks], acc[rt][0], 0,0,0);
        acc[rt][1] = __builtin_amdgcn_mfma_f32_16x16x32_bf16(a, breg[1][ks], acc[rt][1], 0,0,0);
      }
    }
    #pragma unroll
    for (int rt = 0; rt < 4; ++rt)
      #pragma unroll
      for (int ntl = 0; ntl < 2; ++ntl){
        int col = (nt0+ntl)*16 + l15;
        float bvv = b2f(bia[col]);
        #pragma unroll
        for (int j = 0; j < 4; ++j)
          Out[(size_t)(r0 + rbase + rt*16 + l4*4 + j)*DM + col] = f2b(acc[rt][ntl][j] + bvv);
      }
  }
}

// ---------------- MFMA conv/GEMM: 256 thr / 4 waves, BM=64 rows ----------------
// tap-0 B-fragments loaded BEFORE the staging barrier: their latency drains
// inside the barrier's vmcnt(0) wait instead of stalling the first MFMA.
template<int NTAPS, bool RELU, bool RESID>
__global__ __launch_bounds__(256, 4) void conv_gemm(const bf16* __restrict__ A,
                                                    const bf16* __restrict__ Bt,   // [NTAPS][128][128]
                                                    const bf16* __restrict__ bias,
                                                    const bf16* resid,             // may alias Cout
                                                    bf16* Cout){
  constexpr int HT   = NTAPS/2;               // 4 for 9-tap, 0 for 1x1
  constexpr int ROWS = 64 + 2*HT;             // 72 or 64
  __shared__ short8v lds[ROWS*16];            // [row][chunk ^ (row&7)]
  const int tid = threadIdx.x;
  const int r0  = blockIdx.x*64;
  const int t0  = r0 & (TLEN-1);              // block lies inside one (b,v)
  const long mb = r0 - t0;                    // first token of this (b,v)
  const int lane = tid & 63;
  const int wid  = tid >> 6;
  const int nt0  = wid * 2;                   // col-tile pair
  const int l15 = lane & 15, l4 = lane >> 4;

  for (int i = tid; i < ROWS*16; i += 256){
    int row = i >> 4, c0 = i & 15;
    int t = t0 + row - HT;
    if (t < 0) t = 0;
    if (t > TLEN-1) t = TLEN-1;               // clamped rows only feed invalid taps
    lds[row*16 + (c0 ^ (row & 7))] = *reinterpret_cast<const short8v*>(A + (mb + t)*DM + c0*8);
  }
  // hoisted tap-0 B-loads (independent of LDS) -- drain under the barrier
  short8v breg[2][4];
  #pragma unroll
  for (int ntl = 0; ntl < 2; ++ntl)
    #pragma unroll
    for (int ks = 0; ks < 4; ++ks)
      breg[ntl][ks] = *reinterpret_cast<const short8v*>(Bt + ((nt0+ntl)*16 + l15)*DM + ks*32 + l4*8);
  __syncthreads();

  float4v acc[4][2];
  #pragma unroll
  for (int rt = 0; rt < 4; ++rt){ acc[rt][0] = (float4v){0,0,0,0}; acc[rt][1] = (float4v){0,0,0,0}; }

  #pragma unroll
  for (int tap = 0; tap < NTAPS; ++tap){
    if (tap > 0){
      const bf16* Btap = Bt + (size_t)tap*DM*DM;
      #pragma unroll
      for (int ntl = 0; ntl < 2; ++ntl)
        #pragma unroll
        for (int ks = 0; ks < 4; ++ks)
          breg[ntl][ks] = *reinterpret_cast<const short8v*>(Btap + ((nt0+ntl)*16 + l15)*DM + ks*32 + l4*8);
    }
    const int dt = tap - HT;
    #pragma unroll
    for (int rt = 0; rt < 4; ++rt){
      const int tl = rt*16 + l15;             // local output t-offset (0..63)
      bool valid = true;
      if (NTAPS > 1){
        int ts = t0 + tl + dt;
        valid = (ts >= 0) && (ts < TLEN);
      }
      const int ldsRow = tl + HT + dt;        // 0..ROWS-1
      #pragma unroll
      for (int ks = 0; ks < 4; ++ks){
        short8v a = lds[ldsRow*16 + ((ks*4 + l4) ^ (ldsRow & 7))];
        if (NTAPS > 1 && !valid) a = (short8v){0,0,0,0,0,0,0,0};
        acc[rt][0] = __builtin_amdgcn_mfma_f32_16x16x32_bf16(a, breg[0][ks], acc[rt][0], 0,0,0);
        acc[rt][1] = __builtin_amdgcn_mfma_f32_16x16x32_bf16(a, breg[1][ks], acc[rt][1], 0,0,0);
      }
    }
  }
  #pragma unroll
  for (int rt = 0; rt < 4; ++rt){
    #pragma unroll
    for (int ntl = 0; ntl < 2; ++ntl){
      int col = (nt0+ntl)*16 + l15;
      float bv = b2f(bias[col]);
      #pragma unroll
      for (int j = 0; j < 4; ++j){
        size_t idx = (size_t)(r0 + rt*16 + l4*4 + j)*DM + col;
        float val = acc[rt][ntl][j] + bv;
        if (RESID) val += b2f(resid[idx]);     // read-before-write, same thread
        if (RELU) val = fmaxf(val, 0.f);
        Cout[idx] = f2b(val);
      }
    }
  }
}

// ---------------- attention core (r17): MFMA QK^T/PV + fused wo + fused agg ----------------
// LDS pool (aliased):
//   [0      .. 5712 )  sQ  -> sao  [32][136] @0
//   [5712   .. 11424)  sK  -> (sfeat tail)
//   [11424  .. 20128)  sV  -> sfeat[32][136] @8704
//   [20128  .. 27184)  sc f32[1764]
//   [27184  .. 37424)  sP bf16[4][32][40]
//   [37424  .. 38320)  sgb | [38320..39216) sAn | [39216..39552) rmax | [39552..39888) rinv
#define POOLSZ 39936
__global__ __launch_bounds__(256) void attn_core(const bf16* __restrict__ Q,
                                                 const bf16* __restrict__ K,
                                                 const bf16* __restrict__ V,
                                                 const bf16* __restrict__ gbias,
                                                 const bf16* __restrict__ An,
                                                 const bf16* __restrict__ woT,   // [n][k]
                                                 const bf16* __restrict__ bo,
                                                 float* __restrict__ attn_out,
                                                 bf16* __restrict__ feat_out,
                                                 bf16* __restrict__ agg_out){
  __shared__ __align__(16) char pool[POOLSZ];
  bf16*  sQ   = (bf16*) (pool + 0);
  bf16*  sK   = (bf16*) (pool + 5712);
  bf16*  sV   = (bf16*) (pool + 11424);
  float* sc   = (float*)(pool + 20128);
  bf16*  sP   = (bf16*) (pool + 27184);
  bf16*  sgb  = (bf16*) (pool + 37424);
  bf16*  sAn  = (bf16*) (pool + 38320);
  float* rmax = (float*)(pool + 39216);
  float* rinv = (float*)(pool + 39552);
  bf16*  sao  = (bf16*) (pool + 0);       // alias over sQ/sK (dead after scores)
  bf16*  sfeat= (bf16*) (pool + 8704);    // alias over sK-end/sV (sV dead after PV)

  const int n = blockIdx.x;
  const int bb = n / TLEN, t = n % TLEN;
  const int tid = threadIdx.x;
  const int lane = tid & 63;
  const int wid  = tid >> 6;              // wave = head
  const int l15 = lane & 15, l4 = lane >> 4;

  for (int i = tid; i < VJ*VJ; i += 256){ sgb[i] = gbias[i]; sAn[i] = An[i]; }
  for (int i = tid; i < 2*VJ*16; i += 256){
    int c0 = i & 15; int v = (i >> 4) % VJ; int w = i / (16*VJ);
    size_t m = ((size_t)bb*VJ + v)*TLEN + t;
    const bf16* src = (w==0 ? Q : K) + m*DM + c0*8;
    bf16* dst = (w==0 ? sQ : sK) + v*136 + c0*8;
    *reinterpret_cast<short8v*>(dst) = *reinterpret_cast<const short8v*>(src);
  }
  for (int i = tid; i < 32*16; i += 256){
    int c0 = i & 15; int v = i >> 4;
    short8v val = (short8v){0,0,0,0,0,0,0,0};
    if (v < VJ){
      size_t m = ((size_t)bb*VJ + v)*TLEN + t;
      val = *reinterpret_cast<const short8v*>(V + m*DM + c0*8);
    }
    *reinterpret_cast<short8v*>(sV + v*136 + c0*8) = val;   // rows >=21 true zeros
  }
  for (int i = tid; i < 4*32*40/8; i += 256)
    reinterpret_cast<short8v*>(sP)[i] = (short8v){0,0,0,0,0,0,0,0};
  __syncthreads();

  // ---- scores via MFMA: wave h (M=21,N=21,K=32 -> 2x2 tiles) ----
  const float scale = 0.17677669529663687f;   // 1/sqrt(32)
  {
    const int h = wid;
    short8v aq[2], bk2[2];
    #pragma unroll
    for (int mt = 0; mt < 2; ++mt){
      int i = mt*16 + l15; if (i > VJ-1) i = VJ-1;
      aq[mt] = *reinterpret_cast<const short8v*>(sQ + i*136 + h*DH + l4*8);
    }
    #pragma unroll
    for (int nt = 0; nt < 2; ++nt){
      int j = nt*16 + l15; if (j > VJ-1) j = VJ-1;
      bk2[nt] = *reinterpret_cast<const short8v*>(sK + j*136 + h*DH + l4*8);
    }
    float4v cs[2][2];
    #pragma unroll
    for (int mt = 0; mt < 2; ++mt)
      #pragma unroll
      for (int nt = 0; nt < 2; ++nt){
        cs[mt][nt] = (float4v){0,0,0,0};
        cs[mt][nt] = __builtin_amdgcn_mfma_f32_16x16x32_bf16(aq[mt], bk2[nt], cs[mt][nt], 0,0,0);
      }
    #pragma unroll
    for (int mt = 0; mt < 2; ++mt)
      #pragma unroll
      for (int nt = 0; nt < 2; ++nt){
        int j = nt*16 + l15;
        #pragma unroll
        for (int jj = 0; jj < 4; ++jj){
          int i = mt*16 + l4*4 + jj;
          if (i < VJ && j < VJ)
            sc[(h*VJ + i)*VJ + j] = cs[mt][nt][jj]*scale + b2f(sgb[i*VJ + j]);
        }
      }
  }
  __syncthreads();
  // ---- softmax stats ----
  for (int r = tid; r < NH*VJ; r += 256){
    float m = -1e30f;
    for (int j = 0; j < VJ; ++j) m = fmaxf(m, sc[r*VJ + j]);
    float s = 0.f;
    for (int j = 0; j < VJ; ++j) s += __expf(sc[r*VJ + j] - m);
    rmax[r] = m; rinv[r] = 1.0f/s;
  }
  __syncthreads();
  // ---- normalize: write attn_out (f32) + sP (bf16, padded) ----
  for (int idx = tid; idx < NH*VJ*VJ; idx += 256){
    int r = idx / VJ;
    int j = idx % VJ, i2 = r % VJ, h = idx/(VJ*VJ);
    float e = __expf(sc[idx] - rmax[r]) * rinv[r];
    attn_out[(size_t)n*(NH*VJ*VJ) + idx] = e;
    sP[(h*32 + i2)*40 + j] = f2b(e);
  }
  __syncthreads();
  // ---- PV via MFMA: wave h: ao[:, h*32..h*32+31] ----
  float4v cp[2][2];
  {
    const int h = wid;
    short8v pa[2];
    #pragma unroll
    for (int mt = 0; mt < 2; ++mt){
      int i = mt*16 + l15;                      // rows >=21 are zeros
      pa[mt] = *reinterpret_cast<const short8v*>(sP + (h*32 + i)*40 + l4*8);
    }
    short8v bv2[2];
    #pragma unroll
    for (int nt = 0; nt < 2; ++nt){
      #pragma unroll
      for (int e = 0; e < 8; ++e)
        bv2[nt][e] = *reinterpret_cast<const short*>(sV + (l4*8 + e)*136 + h*DH + nt*16 + l15);
    }
    #pragma unroll
    for (int mt = 0; mt < 2; ++mt)
      #pragma unroll
      for (int nt = 0; nt < 2; ++nt){
        cp[mt][nt] = (float4v){0,0,0,0};
        cp[mt][nt] = __builtin_amdgcn_mfma_f32_16x16x32_bf16(pa[mt], bv2[nt], cp[mt][nt], 0,0,0);
      }
  }
  __syncthreads();                              // all PV reads of sV/sP done
  // ---- write ao -> sao; zero rows >= VJ ----
  for (int i = tid; i < (32-VJ)*16; i += 256){
    int row = VJ + i/16, c0 = i & 15;
    *reinterpret_cast<short8v*>(sao + row*136 + c0*8) = (short8v){0,0,0,0,0,0,0,0};
  }
  {
    const int h = wid;
    #pragma unroll
    for (int mt = 0; mt < 2; ++mt)
      #pragma unroll
      for (int nt = 0; nt < 2; ++nt){
        int d = h*DH + nt*16 + l15;
        #pragma unroll
        for (int jj = 0; jj < 4; ++jj){
          int i = mt*16 + l4*4 + jj;
          if (i < VJ) sao[i*136 + d] = f2b(cp[mt][nt][jj]);
        }
      }
  }
  __syncthreads();
  // ---- wo GEMM: M=32, N=128, K=128; 4 waves x 32 cols ----
  float4v acc[2][2];
  #pragma unroll
  for (int mt = 0; mt < 2; ++mt){ acc[mt][0] = (float4v){0,0,0,0}; acc[mt][1] = (float4v){0,0,0,0}; }
  #pragma unroll
  for (int ks = 0; ks < 4; ++ks){
    short8v bfr[2];
    #pragma unroll
    for (int ct = 0; ct < 2; ++ct)
      bfr[ct] = *reinterpret_cast<const short8v*>(woT + (wid*32 + ct*16 + l15)*DM + ks*32 + l4*8);
    #pragma unroll
    for (int mt = 0; mt < 2; ++mt){
      int row = mt*16 + l15;
      short8v a = *reinterpret_cast<const short8v*>(sao + row*136 + ks*32 + l4*8);
      acc[mt][0] = __builtin_amdgcn_mfma_f32_16x16x32_bf16(a, bfr[0], acc[mt][0], 0,0,0);
      acc[mt][1] = __builtin_amdgcn_mfma_f32_16x16x32_bf16(a, bfr[1], acc[mt][1], 0,0,0);
    }
  }
  #pragma unroll
  for (int mt = 0; mt < 2; ++mt){
    #pragma unroll
    for (int ct = 0; ct < 2; ++ct){
      int col = wid*32 + ct*16 + l15;
      float bov = b2f(bo[col]);
      #pragma unroll
      for (int j = 0; j < 4; ++j){
        int row = mt*16 + l4*4 + j;
        float fv = acc[mt][ct][j] + bov;
        sfeat[row*136 + col] = f2b(fv);
        if (row < VJ)
          feat_out[(((size_t)bb*VJ + row)*TLEN + t)*DM + col] = f2b(fv);
      }
    }
  }
  __syncthreads();
  // ---- agg GEMM: agg[w][d] = sum_u An[u][w]*feat[u][d]; K=32 (u>=21 -> afr=0) ----
  float4v acg[2][2];
  #pragma unroll
  for (int mt = 0; mt < 2; ++mt){ acg[mt][0] = (float4v){0,0,0,0}; acg[mt][1] = (float4v){0,0,0,0}; }
  short8v afr[2];
  #pragma unroll
  for (int mt = 0; mt < 2; ++mt){
    int w = mt*16 + l15;
    #pragma unroll
    for (int e = 0; e < 8; ++e){
      int k = l4*8 + e;
      short vsv = 0;
      if (k < VJ && w < VJ) vsv = *reinterpret_cast<const short*>(&sAn[k*VJ + w]);
      afr[mt][e] = vsv;
    }
  }
  #pragma unroll
  for (int ct = 0; ct < 2; ++ct){
    int d = wid*32 + ct*16 + l15;
    short8v bfr;
    #pragma unroll
    for (int e = 0; e < 8; ++e){
      int k = l4*8 + e;
      bfr[e] = *reinterpret_cast<const short*>(sfeat + k*136 + d);
    }
    #pragma unroll
    for (int mt = 0; mt < 2; ++mt)
      acg[mt][ct] = __builtin_amdgcn_mfma_f32_16x16x32_bf16(afr[mt], bfr, acg[mt][ct], 0,0,0);
  }
  #pragma unroll
  for (int mt = 0; mt < 2; ++mt){
    #pragma unroll
    for (int ct = 0; ct < 2; ++ct){
      int col = wid*32 + ct*16 + l15;
      #pragma unroll
      for (int j = 0; j < 4; ++j){
        int w = mt*16 + l4*4 + j;
        if (w < VJ)
          agg_out[(((size_t)bb*VJ + w)*TLEN + t)*DM + col] = f2b(acg[mt][ct][j]);
      }
    }
  }
}

// ---------------- agg: rows at stride TLEN*DM ----------------
__global__ __launch_bounds__(256) void agg_kernel(const bf16* __restrict__ fin,
                                                  const bf16* __restrict__ An,
                                                  bf16* __restrict__ aout){
  const int n = blockIdx.x;
  const int bb = n / TLEN, t = n % TLEN;
  const int tid = threadIdx.x;
  __shared__ bf16 sx[VJ][136];
  __shared__ float sA[VJ*VJ];
  for (int i = tid; i < VJ*VJ; i += 256) sA[i] = b2f(An[i]);
  for (int i = tid; i < VJ*16; i += 256){
    int c0 = i & 15, v = i >> 4;
    size_t m = ((size_t)bb*VJ + v)*TLEN + t;
    *reinterpret_cast<short8v*>(&sx[v][c0*8]) =
      *reinterpret_cast<const short8v*>(fin + m*DM + c0*8);
  }
  __syncthreads();
  for (int i = tid; i < VJ*16; i += 256){
    int c0 = i & 15, w = i >> 4;
    float acc[8] = {0,0,0,0,0,0,0,0};
    #pragma unroll
    for (int u = 0; u < VJ; ++u){
      float a = sA[u*VJ + w];
      short8v xv = *reinterpret_cast<const short8v*>(&sx[u][c0*8]);
      #pragma unroll
      for (int e = 0; e < 8; ++e) acc[e] = fmaf(a, hb2f(xv[e]), acc[e]);
    }
    short8v out;
    #pragma unroll
    for (int e = 0; e < 8; ++e) out[e] = bf2s(acc[e]);
    size_t m = ((size_t)bb*VJ + w)*TLEN + t;
    *reinterpret_cast<short8v*>(aout + m*DM + c0*8) = out;
  }
}

// ---------------- [B,V,T,D] bf16 -> [B,D,T,V] f32 transpose into d_out ----------------
__global__ __launch_bounds__(256) void transpose_out(const bf16* __restrict__ fin,
                                                     float* __restrict__ fout){
  const int bid = blockIdx.x;
  const int b   = bid >> 5;
  const int rem = bid & 31;
  const int t0  = (rem >> 2) * 32;
  const int d0  = (rem & 3) * 32;
  __shared__ bf16 tile[32][VJ][33];
  const int tid = threadIdx.x;
  for (int idx = tid; idx < 32*VJ*32; idx += 256){
    int dl = idx & 31;
    int v  = (idx >> 5) % VJ;
    int tl = idx / (32*VJ);
    tile[tl][v][dl] = fin[(((size_t)b*VJ + v)*TLEN + t0 + tl)*DM + d0 + dl];
  }
  __syncthreads();
  for (int idx = tid; idx < 32*VJ*32; idx += 256){
    int j  = idx % (32*VJ);
    int dl = idx / (32*VJ);
    int tl = j / VJ, v = j % VJ;
    fout[((size_t)(b*DM + d0 + dl)*TLEN + t0 + tl)*VJ + v] = b2f(tile[tl][v][dl]);
  }
}

extern "C" void kernel_launch(void* const* d_in, const int* in_sizes, int n_in,
                              void* d_out, int out_size, void* d_ws, size_t ws_size,
                              hipStream_t stream){
  const size_t featElems = (size_t)MTOK*DM;        // 44,040,192
  float* outf    = (float*)d_out;                  // [B,D,T,V] f32 (final)
  float* attnOut = outf + featElems;               // [N,H,V,V] f32 (final)
  bf16* qbuf = (bf16*)d_out;                       // scratch until transpose_out
  bf16* kbuf = qbuf + featElems;

  char* wp = (char*)d_ws;
  auto alloc = [&](size_t bytes)->char*{ char* p = wp; wp += (bytes + 15) & ~(size_t)15; return p; };
  int*  flag = (int*)alloc(16);
  ConvArgs ca; int total = 0;
  for (int i = 0; i < NIN; ++i){ ca.src[i] = d_in[i]; ca.off[i] = total; total += in_sizes[i]; }
  ca.off[NIN] = total;
  bf16* cin   = (bf16*)alloc((size_t)total*2);
  bf16* wqT   = (bf16*)alloc(DM*DM*2);
  bf16* wkT   = (bf16*)alloc(DM*DM*2);
  bf16* wvT   = (bf16*)alloc(DM*DM*2);
  bf16* woT   = (bf16*)alloc(DM*DM*2);
  bf16* twT1  = (bf16*)alloc(KT*DM*DM*2);
  bf16* twT2  = (bf16*)alloc(KT*DM*DM*2);
  bf16* featA = (bf16*)alloc(featElems*2);         // feat0 / running feature map
  bf16* bufV  = (bf16*)alloc(featElems*2);         // V
  if ((size_t)(wp - (char*)d_ws) > ws_size) return;

  const bf16* x    = cin + ca.off[0];
  const bf16* cw   = cin + ca.off[1];
  const bf16* cb   = cin + ca.off[2];
  const bf16* je   = cin + ca.off[3];
  const bf16* gbias= cin + ca.off[4];
  const bf16* wq   = cin + ca.off[5];
  const bf16* bq   = cin + ca.off[6];
  const bf16* wk   = cin + ca.off[7];
  const bf16* bk   = cin + ca.off[8];
  const bf16* wv   = cin + ca.off[9];
  const bf16* bv   = cin + ca.off[10];
  const bf16* wo   = cin + ca.off[11];
  const bf16* bo   = cin + ca.off[12];
  const bf16* gw1  = cin + ca.off[13];
  const bf16* gb1  = cin + ca.off[14];
  const bf16* tw1  = cin + ca.off[15];
  const bf16* tb1  = cin + ca.off[16];
  const bf16* gw2  = cin + ca.off[17];
  const bf16* gb2  = cin + ca.off[18];
  const bf16* tw2  = cin + ca.off[19];
  const bf16* tb2  = cin + ca.off[20];
  const bf16* An   = cin + ca.off[21];

  const int GB  = MTOK/128;                        // 2688 blocks (qkv)
  const int GB2 = MTOK/64;                         // 5376 blocks (conv)
  hipMemsetAsync(flag, 0, sizeof(int), stream);
  detect_dtype<<<1, 256, 0, stream>>>(d_in[0], in_sizes[0], flag);
  convert_inputs<<<(total + 255)/256, 256, 0, stream>>>(ca, cin, flag, total);
  prep_weights<<<(KT*DM*DM + 255)/256, 256, 0, stream>>>(wq, wk, wv, wo, tw1, tw2,
                                                         wqT, wkT, wvT, woT, twT1, twT2);
  qkv_gemm<<<GB, 512, 0, stream>>>(x, cw, cb, je, wqT, wkT, wvT, bq, bk, bv,
                                   qbuf, kbuf, bufV);
  attn_core<<<NFR, 256, 0, stream>>>(qbuf, kbuf, bufV, gbias, An, woT, bo,
                                     attnOut, featA, qbuf);   // agg1 fused -> qbuf
  // ST-GCN block 1
  conv_gemm<1,true,false><<<GB2, 256, 0, stream>>>(qbuf, gw1, gb1, nullptr, kbuf);
  conv_gemm<9,true,true><<<GB2, 256, 0, stream>>>(kbuf, twT1, tb1, featA, featA);
  // ST-GCN block 2
  agg_kernel<<<NFR, 256, 0, stream>>>(featA, An, qbuf);
  conv_gemm<1,true,false><<<GB2, 256, 0, stream>>>(qbuf, gw2, gb2, nullptr, kbuf);
  conv_gemm<9,true,true><<<GB2, 256, 0, stream>>>(kbuf, twT2, tb2, featA, featA);
  transpose_out<<<BB*(TLEN/32)*(DM/32), 256, 0, stream>>>(featA, outf);
}

// Round 20
// 1179.935 us; speedup vs baseline: 1.1399x; 1.0633x over previous
//
#include <hip/hip_runtime.h>
#include <hip/hip_bf16.h>

typedef __hip_bfloat16 bf16;
typedef __attribute__((ext_vector_type(8))) short short8v;
typedef __attribute__((ext_vector_type(4))) float float4v;

#define BB   64
#define CC   3
#define TLEN 256
#define VJ   21
#define DM   128
#define NH   4
#define DH   32
#define KT   9
#define NFR  (BB*TLEN)
#define MTOK (NFR*VJ)          // 344064 tokens
#define NIN  22

// token layout throughout the pipeline: m = ((b*VJ + v)*TLEN + t)  ("[B,V,T,D]")

__device__ __forceinline__ float b2f(bf16 x){ return __bfloat162float(x); }
__device__ __forceinline__ bf16  f2b(float x){ return __float2bfloat16(x); }
__device__ __forceinline__ float hb2f(short s){ return __uint_as_float(((unsigned)(unsigned short)s) << 16); }
__device__ __forceinline__ float lo16(unsigned u){ return __uint_as_float(u << 16); }
__device__ __forceinline__ float hi16(unsigned u){ return __uint_as_float(u & 0xffff0000u); }
__device__ __forceinline__ short bf2s(float x){ bf16 h = f2b(x); return *reinterpret_cast<short*>(&h); }

// ---------------- input dtype detection ----------------
__global__ void detect_dtype(const void* __restrict__ xin, int nus, int* __restrict__ flag){
  const unsigned short* u = (const unsigned short*)xin;
  int lim = nus < 65536 ? nus : 65536;
  int bad = 0;
  for (int k = threadIdx.x; k < lim; k += 256){
    float f = __uint_as_float(((unsigned)u[k]) << 16);
    if (!(fabsf(f) < 1e6f)) bad = 1;
  }
  if (bad) atomicOr(flag, 1);          // flag!=0 => inputs are float32
}

struct ConvArgs { const void* src[NIN]; int off[NIN+1]; };

__global__ void convert_inputs(ConvArgs a, bf16* __restrict__ dst,
                               const int* __restrict__ flag, int total){
  int i = blockIdx.x*256 + threadIdx.x;
  if (i >= total) return;
  bool isf32 = (*flag != 0);
  int k = 0;
  while (i >= a.off[k+1]) ++k;
  int j = i - a.off[k];
  float v;
  if (isf32) v = ((const float*)a.src[k])[j];
  else       v = __uint_as_float(((unsigned)((const unsigned short*)a.src[k])[j]) << 16);
  dst[i] = f2b(v);
}

// ---------------- weight prep ----------------
__global__ void prep_weights(const bf16* __restrict__ wq, const bf16* __restrict__ wk,
                             const bf16* __restrict__ wv, const bf16* __restrict__ wo,
                             const bf16* __restrict__ tw1, const bf16* __restrict__ tw2,
                             bf16* __restrict__ wqT, bf16* __restrict__ wkT,
                             bf16* __restrict__ wvT, bf16* __restrict__ woT,
                             bf16* __restrict__ twT1, bf16* __restrict__ twT2){
  int i = blockIdx.x*256 + threadIdx.x;
  if (i < DM*DM){
    int d = i >> 7, e = i & 127;            // wT[d][e] = w[e][d]
    wqT[i] = wq[e*DM + d];
    wkT[i] = wk[e*DM + d];
    wvT[i] = wv[e*DM + d];
    woT[i] = wo[e*DM + d];
  }
  if (i < KT*DM*DM){
    int c = i & 127; int d = (i >> 7) & 127; int tap = i >> 14;
    twT1[i] = tw1[(d*DM + c)*KT + tap];     // tw [d][c][kt][1]
    twT2[i] = tw2[(d*DM + c)*KT + tap];
  }
}

// ---------------- fused encode + Q/K/V GEMM (b,v uniform per block) ----------------
__global__ __launch_bounds__(512) void qkv_gemm(const bf16* __restrict__ x,
                                                const bf16* __restrict__ cw,
                                                const bf16* __restrict__ cb,
                                                const bf16* __restrict__ je,
                                                const bf16* __restrict__ BtQ,
                                                const bf16* __restrict__ BtK,
                                                const bf16* __restrict__ BtV,
                                                const bf16* __restrict__ bq,
                                                const bf16* __restrict__ bk,
                                                const bf16* __restrict__ bv,
                                                bf16* __restrict__ Oq,
                                                bf16* __restrict__ Ok,
                                                bf16* __restrict__ Ov){
  __shared__ short8v lds[128*16];
  __shared__ float sxf[128][4];              // [t-row][coord]
  const int tid = threadIdx.x;
  const int r0  = blockIdx.x*128;
  const int bvi = r0 >> 8;                   // token block lies inside one (b,v)
  const int t0  = r0 & (TLEN-1);
  const int blk_b = bvi / VJ, blk_v = bvi % VJ;
  {
    int tok = tid >> 2, c = tid & 3;
    if (tok < 128 && c < 3)
      sxf[tok][c] = b2f(x[((size_t)(blk_b*CC + c)*TLEN + t0 + tok)*VJ + blk_v]);
  }
  __syncthreads();
  for (int i = tid; i < 128*16; i += 512){   // compute feat tile (encode fused)
    int row = i >> 4, c0 = i & 15;
    short8v cw0 = *reinterpret_cast<const short8v*>(cw + 0*DM + c0*8);
    short8v cw1 = *reinterpret_cast<const short8v*>(cw + 1*DM + c0*8);
    short8v cw2 = *reinterpret_cast<const short8v*>(cw + 2*DM + c0*8);
    short8v cbv = *reinterpret_cast<const short8v*>(cb + c0*8);
    short8v jev = *reinterpret_cast<const short8v*>(je + blk_v*DM + c0*8);
    float x0 = sxf[row][0], x1 = sxf[row][1], x2 = sxf[row][2];
    short8v out;
    #pragma unroll
    for (int e = 0; e < 8; ++e){
      float f = hb2f(cbv[e]) + hb2f(jev[e]);
      f = fmaf(x0, hb2f(cw0[e]), f);
      f = fmaf(x1, hb2f(cw1[e]), f);
      f = fmaf(x2, hb2f(cw2[e]), f);
      out[e] = bf2s(f);
    }
    lds[row*16 + (c0 ^ (row & 7))] = out;
  }
  __syncthreads();
  const int lane = tid & 63;
  const int wid  = tid >> 6;
  const int rbase = (wid >> 2) * 64;
  const int nt0   = (wid & 3) * 2;
  const int l15 = lane & 15, l4 = lane >> 4;
  #pragma unroll
  for (int w = 0; w < 3; ++w){
    const bf16* Bt  = (w==0) ? BtQ : (w==1) ? BtK : BtV;
    const bf16* bia = (w==0) ? bq  : (w==1) ? bk  : bv;
    bf16*       Out = (w==0) ? Oq  : (w==1) ? Ok  : Ov;
    short8v breg[2][4];
    #pragma unroll
    for (int ntl = 0; ntl < 2; ++ntl)
      #pragma unroll
      for (int ks = 0; ks < 4; ++ks)
        breg[ntl][ks] = *reinterpret_cast<const short8v*>(Bt + ((nt0+ntl)*16 + l15)*DM + ks*32 + l4*8);
    float4v acc[4][2];
    #pragma unroll
    for (int rt = 0; rt < 4; ++rt){ acc[rt][0] = (float4v){0,0,0,0}; acc[rt][1] = (float4v){0,0,0,0}; }
    #pragma unroll
    for (int rt = 0; rt < 4; ++rt){
      const int ldsRow = rbase + rt*16 + l15;
      #pragma unroll
      for (int ks = 0; ks < 4; ++ks){
        short8v a = lds[ldsRow*16 + ((ks*4 + l4) ^ (ldsRow & 7))];
        acc[rt][0] = __builtin_amdgcn_mfma_f32_16x16x32_bf16(a, breg[0][ks], acc[rt][0], 0,0,0);
        acc[rt][1] = __builtin_amdgcn_mfma_f32_16x16x32_bf16(a, breg[1][ks], acc[rt][1], 0,0,0);
      }
    }
    #pragma unroll
    for (int rt = 0; rt < 4; ++rt)
      #pragma unroll
      for (int ntl = 0; ntl < 2; ++ntl){
        int col = (nt0+ntl)*16 + l15;
        float bvv = b2f(bia[col]);
        #pragma unroll
        for (int j = 0; j < 4; ++j)
          Out[(size_t)(r0 + rbase + rt*16 + l4*4 + j)*DM + col] = f2b(acc[rt][ntl][j] + bvv);
      }
  }
}

// ---------------- MFMA conv/GEMM: 256 thr / 4 waves, BM=64 rows ----------------
template<int NTAPS, bool RELU, bool RESID>
__global__ __launch_bounds__(256, 4) void conv_gemm(const bf16* __restrict__ A,
                                                    const bf16* __restrict__ Bt,   // [NTAPS][128][128]
                                                    const bf16* __restrict__ bias,
                                                    const bf16* resid,             // may alias Cout
                                                    bf16* Cout){
  constexpr int HT   = NTAPS/2;               // 4 for 9-tap, 0 for 1x1
  constexpr int ROWS = 64 + 2*HT;             // 72 or 64
  __shared__ short8v lds[ROWS*16];            // [row][chunk ^ (row&7)]
  const int tid = threadIdx.x;
  const int r0  = blockIdx.x*64;
  const int t0  = r0 & (TLEN-1);              // block lies inside one (b,v)
  const long mb = r0 - t0;                    // first token of this (b,v)
  for (int i = tid; i < ROWS*16; i += 256){
    int row = i >> 4, c0 = i & 15;
    int t = t0 + row - HT;
    if (t < 0) t = 0;
    if (t > TLEN-1) t = TLEN-1;               // clamped rows only feed invalid taps
    lds[row*16 + (c0 ^ (row & 7))] = *reinterpret_cast<const short8v*>(A + (mb + t)*DM + c0*8);
  }
  __syncthreads();
  const int lane = tid & 63;
  const int wid  = tid >> 6;
  const int nt0  = wid * 2;                   // col-tile pair
  const int l15 = lane & 15, l4 = lane >> 4;
  float4v acc[4][2];
  #pragma unroll
  for (int rt = 0; rt < 4; ++rt){ acc[rt][0] = (float4v){0,0,0,0}; acc[rt][1] = (float4v){0,0,0,0}; }

  #pragma unroll
  for (int tap = 0; tap < NTAPS; ++tap){
    const bf16* Btap = Bt + (size_t)tap*DM*DM;
    short8v breg[2][4];
    #pragma unroll
    for (int ntl = 0; ntl < 2; ++ntl)
      #pragma unroll
      for (int ks = 0; ks < 4; ++ks)
        breg[ntl][ks] = *reinterpret_cast<const short8v*>(Btap + ((nt0+ntl)*16 + l15)*DM + ks*32 + l4*8);
    const int dt = tap - HT;
    #pragma unroll
    for (int rt = 0; rt < 4; ++rt){
      const int tl = rt*16 + l15;             // local output t-offset (0..63)
      bool valid = true;
      if (NTAPS > 1){
        int ts = t0 + tl + dt;
        valid = (ts >= 0) && (ts < TLEN);
      }
      const int ldsRow = tl + HT + dt;        // 0..ROWS-1
      #pragma unroll
      for (int ks = 0; ks < 4; ++ks){
        short8v a = lds[ldsRow*16 + ((ks*4 + l4) ^ (ldsRow & 7))];
        if (NTAPS > 1 && !valid) a = (short8v){0,0,0,0,0,0,0,0};
        acc[rt][0] = __builtin_amdgcn_mfma_f32_16x16x32_bf16(a, breg[0][ks], acc[rt][0], 0,0,0);
        acc[rt][1] = __builtin_amdgcn_mfma_f32_16x16x32_bf16(a, breg[1][ks], acc[rt][1], 0,0,0);
      }
    }
  }
  #pragma unroll
  for (int rt = 0; rt < 4; ++rt){
    #pragma unroll
    for (int ntl = 0; ntl < 2; ++ntl){
      int col = (nt0+ntl)*16 + l15;
      float bv = b2f(bias[col]);
      #pragma unroll
      for (int j = 0; j < 4; ++j){
        size_t idx = (size_t)(r0 + rt*16 + l4*4 + j)*DM + col;
        float val = acc[rt][ntl][j] + bv;
        if (RESID) val += b2f(resid[idx]);     // read-before-write, same thread
        if (RELU) val = fmaxf(val, 0.f);
        Cout[idx] = f2b(val);
      }
    }
  }
}

// ---------------- attention core v4: MFMA QK^T + MFMA PV + fused wo + fused agg ----------------
// LDS pool layout (aliased):
//   [0      .. 5712 )  sQ [21][136]      (dead after scores)   } reused: sao  [32][136] @0
//   [5712   .. 11424)  sK [21][136]      (dead after scores)   }         sfeat[32][136] @8704
//   [11424  .. 20128)  sV [32][136]      (dead after PV)       }
//   [20128  .. 27184)  sc f32[1764]
//   [27184  .. 37424)  sP bf16[4][32][40]
//   [37424  .. 38320)  sgb bf16[441]
//   [38320  .. 39216)  sAn bf16[441]
//   [39216  .. 39552)  rmax f32[84]
//   [39552  .. 39888)  rinv f32[84]
#define POOLSZ 39936
__global__ __launch_bounds__(256) void attn_core(const bf16* __restrict__ Q,
                                                 const bf16* __restrict__ K,
                                                 const bf16* __restrict__ V,
                                                 const bf16* __restrict__ gbias,
                                                 const bf16* __restrict__ An,
                                                 const bf16* __restrict__ woT,   // [n][k]
                                                 const bf16* __restrict__ bo,
                                                 float* __restrict__ attn_out,
                                                 bf16* __restrict__ feat_out,
                                                 bf16* __restrict__ agg_out){
  __shared__ __align__(16) char pool[POOLSZ];
  bf16*  sQ   = (bf16*) (pool + 0);
  bf16*  sK   = (bf16*) (pool + 5712);
  bf16*  sV   = (bf16*) (pool + 11424);
  float* sc   = (float*)(pool + 20128);
  bf16*  sP   = (bf16*) (pool + 27184);
  bf16*  sgb  = (bf16*) (pool + 37424);
  bf16*  sAn  = (bf16*) (pool + 38320);
  float* rmax = (float*)(pool + 39216);
  float* rinv = (float*)(pool + 39552);
  bf16*  sao  = (bf16*) (pool + 0);       // alias over sQ/sK (dead after scores)
  bf16*  sfeat= (bf16*) (pool + 8704);    // alias over sK-end/sV (sV dead after PV)

  const int n = blockIdx.x;
  const int bb = n / TLEN, t = n % TLEN;
  const int tid = threadIdx.x;
  const int lane = tid & 63;
  const int wid  = tid >> 6;              // wave = head
  const int l15 = lane & 15, l4 = lane >> 4;

  for (int i = tid; i < VJ*VJ; i += 256){ sgb[i] = gbias[i]; sAn[i] = An[i]; }
  for (int i = tid; i < 2*VJ*16; i += 256){
    int c0 = i & 15; int v = (i >> 4) % VJ; int w = i / (16*VJ);
    size_t m = ((size_t)bb*VJ + v)*TLEN + t;
    const bf16* src = (w==0 ? Q : K) + m*DM + c0*8;
    bf16* dst = (w==0 ? sQ : sK) + v*136 + c0*8;
    *reinterpret_cast<short8v*>(dst) = *reinterpret_cast<const short8v*>(src);
  }
  for (int i = tid; i < 32*16; i += 256){
    int c0 = i & 15; int v = i >> 4;
    short8v val = (short8v){0,0,0,0,0,0,0,0};
    if (v < VJ){
      size_t m = ((size_t)bb*VJ + v)*TLEN + t;
      val = *reinterpret_cast<const short8v*>(V + m*DM + c0*8);
    }
    *reinterpret_cast<short8v*>(sV + v*136 + c0*8) = val;   // rows >=21 true zeros
  }
  for (int i = tid; i < 4*32*40/8; i += 256)
    reinterpret_cast<short8v*>(sP)[i] = (short8v){0,0,0,0,0,0,0,0};
  __syncthreads();

  // ---- scores via MFMA: wave h computes head h (M=21,N=21,K=32 -> 2x2 tiles) ----
  const float scale = 0.17677669529663687f;   // 1/sqrt(32)
  {
    const int h = wid;
    short8v aq[2], bk2[2];
    #pragma unroll
    for (int mt = 0; mt < 2; ++mt){
      int i = mt*16 + l15; if (i > VJ-1) i = VJ-1;
      aq[mt] = *reinterpret_cast<const short8v*>(sQ + i*136 + h*DH + l4*8);
    }
    #pragma unroll
    for (int nt = 0; nt < 2; ++nt){
      int j = nt*16 + l15; if (j > VJ-1) j = VJ-1;
      bk2[nt] = *reinterpret_cast<const short8v*>(sK + j*136 + h*DH + l4*8);
    }
    float4v cs[2][2];
    #pragma unroll
    for (int mt = 0; mt < 2; ++mt)
      #pragma unroll
      for (int nt = 0; nt < 2; ++nt){
        cs[mt][nt] = (float4v){0,0,0,0};
        cs[mt][nt] = __builtin_amdgcn_mfma_f32_16x16x32_bf16(aq[mt], bk2[nt], cs[mt][nt], 0,0,0);
      }
    #pragma unroll
    for (int mt = 0; mt < 2; ++mt)
      #pragma unroll
      for (int nt = 0; nt < 2; ++nt){
        int j = nt*16 + l15;
        #pragma unroll
        for (int jj = 0; jj < 4; ++jj){
          int i = mt*16 + l4*4 + jj;
          if (i < VJ && j < VJ)
            sc[(h*VJ + i)*VJ + j] = cs[mt][nt][jj]*scale + b2f(sgb[i*VJ + j]);
        }
      }
  }
  __syncthreads();
  // ---- softmax stats ----
  for (int r = tid; r < NH*VJ; r += 256){
    float m = -1e30f;
    for (int j = 0; j < VJ; ++j) m = fmaxf(m, sc[r*VJ + j]);
    float s = 0.f;
    for (int j = 0; j < VJ; ++j) s += __expf(sc[r*VJ + j] - m);
    rmax[r] = m; rinv[r] = 1.0f/s;
  }
  __syncthreads();
  // ---- normalize: write attn_out (f32) + sP (bf16, padded) ----
  for (int idx = tid; idx < NH*VJ*VJ; idx += 256){
    int r = idx / VJ;
    int j = idx % VJ, i2 = r % VJ, h = idx/(VJ*VJ);
    float e = __expf(sc[idx] - rmax[r]) * rinv[r];
    attn_out[(size_t)n*(NH*VJ*VJ) + idx] = e;
    sP[(h*32 + i2)*40 + j] = f2b(e);
  }
  __syncthreads();
  // ---- PV via MFMA: wave h: ao[:, h*32..h*32+31] (M=21 pad 32, N=32, K=32) ----
  float4v cp[2][2];
  {
    const int h = wid;
    short8v pa[2];
    #pragma unroll
    for (int mt = 0; mt < 2; ++mt){
      int i = mt*16 + l15;                      // rows >=21 are zeros
      pa[mt] = *reinterpret_cast<const short8v*>(sP + (h*32 + i)*40 + l4*8);
    }
    short8v bv2[2];
    #pragma unroll
    for (int nt = 0; nt < 2; ++nt){
      #pragma unroll
      for (int e = 0; e < 8; ++e)
        bv2[nt][e] = *reinterpret_cast<const short*>(sV + (l4*8 + e)*136 + h*DH + nt*16 + l15);
    }
    #pragma unroll
    for (int mt = 0; mt < 2; ++mt)
      #pragma unroll
      for (int nt = 0; nt < 2; ++nt){
        cp[mt][nt] = (float4v){0,0,0,0};
        cp[mt][nt] = __builtin_amdgcn_mfma_f32_16x16x32_bf16(pa[mt], bv2[nt], cp[mt][nt], 0,0,0);
      }
  }
  __syncthreads();                              // all PV reads of sV/sP done
  // ---- write ao -> sao (plain [32][136]); zero rows >= VJ ----
  for (int i = tid; i < (32-VJ)*16; i += 256){
    int row = VJ + i/16, c0 = i & 15;
    *reinterpret_cast<short8v*>(sao + row*136 + c0*8) = (short8v){0,0,0,0,0,0,0,0};
  }
  {
    const int h = wid;
    #pragma unroll
    for (int mt = 0; mt < 2; ++mt)
      #pragma unroll
      for (int nt = 0; nt < 2; ++nt){
        int d = h*DH + nt*16 + l15;
        #pragma unroll
        for (int jj = 0; jj < 4; ++jj){
          int i = mt*16 + l4*4 + jj;
          if (i < VJ) sao[i*136 + d] = f2b(cp[mt][nt][jj]);
        }
      }
  }
  __syncthreads();
  // ---- wo GEMM: M=32, N=128, K=128; 4 waves x 32 cols ----
  float4v acc[2][2];
  #pragma unroll
  for (int mt = 0; mt < 2; ++mt){ acc[mt][0] = (float4v){0,0,0,0}; acc[mt][1] = (float4v){0,0,0,0}; }
  #pragma unroll
  for (int ks = 0; ks < 4; ++ks){
    short8v bfr[2];
    #pragma unroll
    for (int ct = 0; ct < 2; ++ct)
      bfr[ct] = *reinterpret_cast<const short8v*>(woT + (wid*32 + ct*16 + l15)*DM + ks*32 + l4*8);
    #pragma unroll
    for (int mt = 0; mt < 2; ++mt){
      int row = mt*16 + l15;
      short8v a = *reinterpret_cast<const short8v*>(sao + row*136 + ks*32 + l4*8);
      acc[mt][0] = __builtin_amdgcn_mfma_f32_16x16x32_bf16(a, bfr[0], acc[mt][0], 0,0,0);
      acc[mt][1] = __builtin_amdgcn_mfma_f32_16x16x32_bf16(a, bfr[1], acc[mt][1], 0,0,0);
    }
  }
  // write feat (rows<21) to global AND all 32 rows to sfeat (finite) for the agg GEMM
  #pragma unroll
  for (int mt = 0; mt < 2; ++mt){
    #pragma unroll
    for (int ct = 0; ct < 2; ++ct){
      int col = wid*32 + ct*16 + l15;
      float bov = b2f(bo[col]);
      #pragma unroll
      for (int j = 0; j < 4; ++j){
        int row = mt*16 + l4*4 + j;
        float fv = acc[mt][ct][j] + bov;
        sfeat[row*136 + col] = f2b(fv);
        if (row < VJ)
          feat_out[(((size_t)bb*VJ + row)*TLEN + t)*DM + col] = f2b(fv);
      }
    }
  }
  __syncthreads();
  // ---- agg GEMM: agg[w][d] = sum_u An[u][w]*feat[u][d]; M=32(w), N=128(d), K=32 (u>=21 -> afr=0) ----
  float4v acg[2][2];
  #pragma unroll
  for (int mt = 0; mt < 2; ++mt){ acg[mt][0] = (float4v){0,0,0,0}; acg[mt][1] = (float4v){0,0,0,0}; }
  short8v afr[2];     // A-fragment: afr[mt][e] = An[k][w], k = l4*8+e, w = mt*16+l15
  #pragma unroll
  for (int mt = 0; mt < 2; ++mt){
    int w = mt*16 + l15;
    #pragma unroll
    for (int e = 0; e < 8; ++e){
      int k = l4*8 + e;
      short vsv = 0;
      if (k < VJ && w < VJ) vsv = *reinterpret_cast<const short*>(&sAn[k*VJ + w]);
      afr[mt][e] = vsv;
    }
  }
  #pragma unroll
  for (int ct = 0; ct < 2; ++ct){
    int d = wid*32 + ct*16 + l15;
    short8v bfr;
    #pragma unroll
    for (int e = 0; e < 8; ++e){
      int k = l4*8 + e;
      bfr[e] = *reinterpret_cast<const short*>(sfeat + k*136 + d);
    }
    #pragma unroll
    for (int mt = 0; mt < 2; ++mt)
      acg[mt][ct] = __builtin_amdgcn_mfma_f32_16x16x32_bf16(afr[mt], bfr, acg[mt][ct], 0,0,0);
  }
  #pragma unroll
  for (int mt = 0; mt < 2; ++mt){
    #pragma unroll
    for (int ct = 0; ct < 2; ++ct){
      int col = wid*32 + ct*16 + l15;
      #pragma unroll
      for (int j = 0; j < 4; ++j){
        int w = mt*16 + l4*4 + j;
        if (w < VJ)
          agg_out[(((size_t)bb*VJ + w)*TLEN + t)*DM + col] = f2b(acg[mt][ct][j]);
      }
    }
  }
}

// ---------------- agg: rows at stride TLEN*DM ----------------
__global__ __launch_bounds__(256) void agg_kernel(const bf16* __restrict__ fin,
                                                  const bf16* __restrict__ An,
                                                  bf16* __restrict__ aout){
  const int n = blockIdx.x;
  const int bb = n / TLEN, t = n % TLEN;
  const int tid = threadIdx.x;
  __shared__ bf16 sx[VJ][136];
  __shared__ float sA[VJ*VJ];
  for (int i = tid; i < VJ*VJ; i += 256) sA[i] = b2f(An[i]);
  for (int i = tid; i < VJ*16; i += 256){
    int c0 = i & 15, v = i >> 4;
    size_t m = ((size_t)bb*VJ + v)*TLEN + t;
    *reinterpret_cast<short8v*>(&sx[v][c0*8]) =
      *reinterpret_cast<const short8v*>(fin + m*DM + c0*8);
  }
  __syncthreads();
  for (int i = tid; i < VJ*16; i += 256){
    int c0 = i & 15, w = i >> 4;
    float acc[8] = {0,0,0,0,0,0,0,0};
    #pragma unroll
    for (int u = 0; u < VJ; ++u){
      float a = sA[u*VJ + w];
      short8v xv = *reinterpret_cast<const short8v*>(&sx[u][c0*8]);
      #pragma unroll
      for (int e = 0; e < 8; ++e) acc[e] = fmaf(a, hb2f(xv[e]), acc[e]);
    }
    short8v out;
    #pragma unroll
    for (int e = 0; e < 8; ++e) out[e] = bf2s(acc[e]);
    size_t m = ((size_t)bb*VJ + w)*TLEN + t;
    *reinterpret_cast<short8v*>(aout + m*DM + c0*8) = out;
  }
}

// ---------------- [B,V,T,D] bf16 -> [B,D,T,V] f32 transpose into d_out ----------------
__global__ __launch_bounds__(256) void transpose_out(const bf16* __restrict__ fin,
                                                     float* __restrict__ fout){
  const int bid = blockIdx.x;
  const int b   = bid >> 5;
  const int rem = bid & 31;
  const int t0  = (rem >> 2) * 32;
  const int d0  = (rem & 3) * 32;
  __shared__ bf16 tile[32][VJ][33];
  const int tid = threadIdx.x;
  for (int idx = tid; idx < 32*VJ*32; idx += 256){
    int dl = idx & 31;
    int v  = (idx >> 5) % VJ;
    int tl = idx / (32*VJ);
    tile[tl][v][dl] = fin[(((size_t)b*VJ + v)*TLEN + t0 + tl)*DM + d0 + dl];
  }
  __syncthreads();
  for (int idx = tid; idx < 32*VJ*32; idx += 256){
    int j  = idx % (32*VJ);
    int dl = idx / (32*VJ);
    int tl = j / VJ, v = j % VJ;
    fout[((size_t)(b*DM + d0 + dl)*TLEN + t0 + tl)*VJ + v] = b2f(tile[tl][v][dl]);
  }
}

extern "C" void kernel_launch(void* const* d_in, const int* in_sizes, int n_in,
                              void* d_out, int out_size, void* d_ws, size_t ws_size,
                              hipStream_t stream){
  const size_t featElems = (size_t)MTOK*DM;        // 44,040,192
  float* outf    = (float*)d_out;                  // [B,D,T,V] f32 (final)
  float* attnOut = outf + featElems;               // [N,H,V,V] f32 (final)
  bf16* qbuf = (bf16*)d_out;                       // scratch until transpose_out
  bf16* kbuf = qbuf + featElems;

  char* wp = (char*)d_ws;
  auto alloc = [&](size_t bytes)->char*{ char* p = wp; wp += (bytes + 15) & ~(size_t)15; return p; };
  int*  flag = (int*)alloc(16);
  ConvArgs ca; int total = 0;
  for (int i = 0; i < NIN; ++i){ ca.src[i] = d_in[i]; ca.off[i] = total; total += in_sizes[i]; }
  ca.off[NIN] = total;
  bf16* cin   = (bf16*)alloc((size_t)total*2);
  bf16* wqT   = (bf16*)alloc(DM*DM*2);
  bf16* wkT   = (bf16*)alloc(DM*DM*2);
  bf16* wvT   = (bf16*)alloc(DM*DM*2);
  bf16* woT   = (bf16*)alloc(DM*DM*2);
  bf16* twT1  = (bf16*)alloc(KT*DM*DM*2);
  bf16* twT2  = (bf16*)alloc(KT*DM*DM*2);
  bf16* featA = (bf16*)alloc(featElems*2);         // feat0 / running feature map
  bf16* bufV  = (bf16*)alloc(featElems*2);         // V
  if ((size_t)(wp - (char*)d_ws) > ws_size) return;

  const bf16* x    = cin + ca.off[0];
  const bf16* cw   = cin + ca.off[1];
  const bf16* cb   = cin + ca.off[2];
  const bf16* je   = cin + ca.off[3];
  const bf16* gbias= cin + ca.off[4];
  const bf16* wq   = cin + ca.off[5];
  const bf16* bq   = cin + ca.off[6];
  const bf16* wk   = cin + ca.off[7];
  const bf16* bk   = cin + ca.off[8];
  const bf16* wv   = cin + ca.off[9];
  const bf16* bv   = cin + ca.off[10];
  const bf16* wo   = cin + ca.off[11];
  const bf16* bo   = cin + ca.off[12];
  const bf16* gw1  = cin + ca.off[13];
  const bf16* gb1  = cin + ca.off[14];
  const bf16* tw1  = cin + ca.off[15];
  const bf16* tb1  = cin + ca.off[16];
  const bf16* gw2  = cin + ca.off[17];
  const bf16* gb2  = cin + ca.off[18];
  const bf16* tw2  = cin + ca.off[19];
  const bf16* tb2  = cin + ca.off[20];
  const bf16* An   = cin + ca.off[21];

  const int GB  = MTOK/128;                        // 2688 blocks (qkv)
  const int GB2 = MTOK/64;                         // 5376 blocks (conv)
  hipMemsetAsync(flag, 0, sizeof(int), stream);
  detect_dtype<<<1, 256, 0, stream>>>(d_in[0], in_sizes[0], flag);
  convert_inputs<<<(total + 255)/256, 256, 0, stream>>>(ca, cin, flag, total);
  prep_weights<<<(KT*DM*DM + 255)/256, 256, 0, stream>>>(wq, wk, wv, wo, tw1, tw2,
                                                         wqT, wkT, wvT, woT, twT1, twT2);
  qkv_gemm<<<GB, 512, 0, stream>>>(x, cw, cb, je, wqT, wkT, wvT, bq, bk, bv,
                                   qbuf, kbuf, bufV);
  attn_core<<<NFR, 256, 0, stream>>>(qbuf, kbuf, bufV, gbias, An, woT, bo,
                                     attnOut, featA, qbuf);   // agg1 fused -> qbuf
  // ST-GCN block 1
  conv_gemm<1,true,false><<<GB2, 256, 0, stream>>>(qbuf, gw1, gb1, nullptr, kbuf);
  conv_gemm<9,true,true><<<GB2, 256, 0, stream>>>(kbuf, twT1, tb1, featA, featA);
  // ST-GCN block 2
  agg_kernel<<<NFR, 256, 0, stream>>>(featA, An, qbuf);
  conv_gemm<1,true,false><<<GB2, 256, 0, stream>>>(qbuf, gw2, gb2, nullptr, kbuf);
  conv_gemm<9,true,true><<<GB2, 256, 0, stream>>>(kbuf, twT2, tb2, featA, featA);
  transpose_out<<<BB*(TLEN/32)*(DM/32), 256, 0, stream>>>(featA, outf);
}